// Round 1
// baseline (101.233 us; speedup 1.0000x reference)
//
#include <hip/hip_runtime.h>

#define CCH 256
#define HH 512
#define WW 512
#define HWSZ (HH * WW)
#define FH 256
#define FW 256
#define LTOT (FH * FW)
#define EPSV 1e-6f

// Phase 1: per-patch squared-distance accumulation over channels + argmax.
// Grid: FH blocks (one per patch row). Block: 1024 threads = 4 channel-groups x 256 patches.
__global__ __launch_bounds__(1024) void dist_kernel(const float* __restrict__ x,
                                                    unsigned char* __restrict__ idx) {
    const int tid = threadIdx.x;
    const int j = tid & 255;       // patch column
    const int g = tid >> 8;        // channel group 0..3
    const int i = blockIdx.x;      // patch row

    const float* p0 = x + (size_t)(2 * i) * WW + 2 * j;
    float d0 = 0.f, d1 = 0.f, d2 = 0.f, d3 = 0.f;

#pragma unroll 4
    for (int c = g; c < CCH; c += 4) {
        const float* pc = p0 + (size_t)c * HWSZ;
        const float2 a = *(const float2*)(pc);        // top row of patch: e0, e1
        const float2 b = *(const float2*)(pc + WW);   // bottom row:      e2, e3
        const float m = (a.x + a.y + b.x + b.y) * 0.25f;
        const float e0 = a.x - m + EPSV;
        const float e1 = a.y - m + EPSV;
        const float e2 = b.x - m + EPSV;
        const float e3 = b.y - m + EPSV;
        d0 += e0 * e0;
        d1 += e1 * e1;
        d2 += e2 * e2;
        d3 += e3 * e3;
    }

    __shared__ float4 sd[4][256];   // 16 KiB
    sd[g][j] = make_float4(d0, d1, d2, d3);
    __syncthreads();

    if (g == 0) {
        const float4 s0 = sd[0][j];
        const float4 s1 = sd[1][j];
        const float4 s2 = sd[2][j];
        const float4 s3 = sd[3][j];
        const float D0 = s0.x + s1.x + s2.x + s3.x;
        const float D1 = s0.y + s1.y + s2.y + s3.y;
        const float D2 = s0.z + s1.z + s2.z + s3.z;
        const float D3 = s0.w + s1.w + s2.w + s3.w;
        // first-max wins (matches jnp.argmax tie semantics)
        int best = 0;
        float bv = D0;
        if (D1 > bv) { bv = D1; best = 1; }
        if (D2 > bv) { bv = D2; best = 2; }
        if (D3 > bv) { bv = D3; best = 3; }
        idx[i * FW + j] = (unsigned char)best;
    }
}

// Phase 2: gather the selected corner for every (c, l). One thread per output element.
__global__ __launch_bounds__(256) void gather_kernel(const float* __restrict__ x,
                                                     const unsigned char* __restrict__ idx,
                                                     float* __restrict__ out) {
    const int t = blockIdx.x * 256 + threadIdx.x;   // t in [0, CCH*LTOT)
    const int c = t >> 16;        // LTOT == 65536
    const int l = t & (LTOT - 1);
    const int e = idx[l];
    const int i = l >> 8;         // FW == 256
    const int j = l & 255;
    const int row = 2 * i + (e >> 1);
    const float2 v = *(const float2*)(x + (size_t)c * HWSZ + (size_t)row * WW + 2 * j);
    out[t] = (e & 1) ? v.y : v.x;
}

extern "C" void kernel_launch(void* const* d_in, const int* in_sizes, int n_in,
                              void* d_out, int out_size, void* d_ws, size_t ws_size,
                              hipStream_t stream) {
    const float* x = (const float*)d_in[0];
    float* out = (float*)d_out;
    unsigned char* idx = (unsigned char*)d_ws;   // LTOT bytes

    dist_kernel<<<FH, 1024, 0, stream>>>(x, idx);
    gather_kernel<<<(CCH * LTOT) / 256, 256, 0, stream>>>(x, idx, out);
}

// Round 2
// 83.960 us; speedup vs baseline: 1.2057x; 1.2057x over previous
//
#include <hip/hip_runtime.h>

#define CCH 256
#define WW 512
#define HWSZ (512 * 512)
#define LTOT 65536
#define EPSV 1e-6f
#define TP 16          // patches per block (one row, 16 consecutive patch columns)
#define NTHREADS 512

// Fully fused: one block owns 16 patches across ALL 256 channels.
// Thread t: k = t&7 (float4 column-quad -> patches 2k,2k+1), cb = t>>3 (channel base),
// iterates 4 channels (cb + 64*it), KEEPING the loaded float4 pairs in registers.
// Per-patch squared-distance sums reduced via shfl_xor (within wave) + LDS (across waves),
// argmax by 16 threads, then every thread selects from its kept registers and stores.
__global__ __launch_bounds__(NTHREADS) void fused_kernel(const float* __restrict__ x,
                                                         float* __restrict__ out) {
    const int t = threadIdx.x;
    const int k = t & 7;           // quad index: covers patches 2k, 2k+1
    const int cb = t >> 3;         // 0..63
    const int l0 = blockIdx.x * TP;
    const int i = l0 >> 8;         // patch row
    const int j0 = l0 & 255;       // patch col base (multiple of TP)

    const float* base = x + (size_t)(2 * i) * WW + 2 * j0 + 4 * k;

    float4 A[4], B[4];
    float s0 = 0.f, s1 = 0.f, s2 = 0.f, s3 = 0.f;
    float s4 = 0.f, s5 = 0.f, s6 = 0.f, s7 = 0.f;

#pragma unroll
    for (int it = 0; it < 4; ++it) {
        const int c = cb + 64 * it;
        const float* pc = base + (size_t)c * HWSZ;
        const float4 a = *(const float4*)(pc);        // row 2i  : patches 2k(e0,e1 in .x,.y), 2k+1(.z,.w)
        const float4 b = *(const float4*)(pc + WW);   // row 2i+1: e2,e3
        A[it] = a;
        B[it] = b;
        const float m0 = (a.x + a.y + b.x + b.y) * 0.25f;
        const float m1 = (a.z + a.w + b.z + b.w) * 0.25f;
        float e;
        e = a.x - m0 + EPSV; s0 += e * e;
        e = a.y - m0 + EPSV; s1 += e * e;
        e = b.x - m0 + EPSV; s2 += e * e;
        e = b.y - m0 + EPSV; s3 += e * e;
        e = a.z - m1 + EPSV; s4 += e * e;
        e = a.w - m1 + EPSV; s5 += e * e;
        e = b.z - m1 + EPSV; s6 += e * e;
        e = b.w - m1 + EPSV; s7 += e * e;
    }

    // Reduce across the 8 channel-bases within each wave (lane bits 3,4,5).
#pragma unroll
    for (int off = 8; off <= 32; off <<= 1) {
        s0 += __shfl_xor(s0, off);
        s1 += __shfl_xor(s1, off);
        s2 += __shfl_xor(s2, off);
        s3 += __shfl_xor(s3, off);
        s4 += __shfl_xor(s4, off);
        s5 += __shfl_xor(s5, off);
        s6 += __shfl_xor(s6, off);
        s7 += __shfl_xor(s7, off);
    }

    __shared__ float part[8][8][8];   // [wave][k][patchhalf*4 + e]  (2 KiB)
    __shared__ int sidx[TP];

    const int wave = t >> 6;
    if ((t & 63) < 8) {               // lane == k carrier (lanes 0..7 have k=0..7)
        float* p = part[wave][k];
        p[0] = s0; p[1] = s1; p[2] = s2; p[3] = s3;
        p[4] = s4; p[5] = s5; p[6] = s6; p[7] = s7;
    }
    __syncthreads();

    if (t < TP) {                     // one thread per patch: sum 8 waves, argmax of 4
        const int kk = t >> 1;
        const int hf = (t & 1) * 4;
        float D0 = 0.f, D1 = 0.f, D2 = 0.f, D3 = 0.f;
#pragma unroll
        for (int w = 0; w < 8; ++w) {
            D0 += part[w][kk][hf + 0];
            D1 += part[w][kk][hf + 1];
            D2 += part[w][kk][hf + 2];
            D3 += part[w][kk][hf + 3];
        }
        int best = 0;
        float bv = D0;
        if (D1 > bv) { bv = D1; best = 1; }
        if (D2 > bv) { bv = D2; best = 2; }
        if (D3 > bv) { bv = D3; best = 3; }
        sidx[t] = best;
    }
    __syncthreads();

    const int e0 = sidx[2 * k];
    const int e1 = sidx[2 * k + 1];

#pragma unroll
    for (int it = 0; it < 4; ++it) {
        const int c = cb + 64 * it;
        const float4 a = A[it];
        const float4 b = B[it];
        const float v0 = (e0 == 0) ? a.x : (e0 == 1) ? a.y : (e0 == 2) ? b.x : b.y;
        const float v1 = (e1 == 0) ? a.z : (e1 == 1) ? a.w : (e1 == 2) ? b.z : b.w;
        *(float2*)(out + (size_t)c * LTOT + l0 + 2 * k) = make_float2(v0, v1);
    }
}

extern "C" void kernel_launch(void* const* d_in, const int* in_sizes, int n_in,
                              void* d_out, int out_size, void* d_ws, size_t ws_size,
                              hipStream_t stream) {
    const float* x = (const float*)d_in[0];
    float* out = (float*)d_out;
    fused_kernel<<<LTOT / TP, NTHREADS, 0, stream>>>(x, out);
}

// Round 3
// 57.817 us; speedup vs baseline: 1.7509x; 1.4522x over previous
//
#include <hip/hip_runtime.h>

#define WW 512
#define HWSZ (512 * 512)
#define LTOT 65536
#define EPSV 1e-6f
#define TP 64            // patches per block (one row, 64 consecutive patch columns = 512B/row)
#define NTHREADS 1024

typedef float v2f __attribute__((ext_vector_type(2)));

// One block owns 64 patches (128 input columns) across ALL 256 channels.
// Thread t: k = t&31 (float4 quad -> patches 2k,2k+1), cb = t>>5 (channel base 0..31),
// channels c = cb + 32*it for it=0..7; float4 row pairs KEPT in registers (64 floats).
// Wave-load = 2 contiguous 512B segments (lanes 0-31 one channel-row, 32-63 the next).
__global__ __launch_bounds__(NTHREADS) void fused_kernel(const float* __restrict__ x,
                                                         float* __restrict__ out) {
    const int t = threadIdx.x;
    const int k = t & 31;          // quad index: columns 4k..4k+3 -> patches 2k, 2k+1
    const int cb = t >> 5;         // 0..31
    const int l0 = blockIdx.x * TP;
    const int i = l0 >> 8;         // patch row
    const int j0 = l0 & 255;       // patch col base (multiple of 64)

    const float* base = x + (size_t)(2 * i) * WW + 2 * j0 + 4 * k;

    float4 A[8], B[8];
    float s0 = 0.f, s1 = 0.f, s2 = 0.f, s3 = 0.f;
    float s4 = 0.f, s5 = 0.f, s6 = 0.f, s7 = 0.f;

#pragma unroll
    for (int it = 0; it < 8; ++it) {
        const int c = cb + 32 * it;
        const float* pc = base + (size_t)c * HWSZ;
        const float4 a = *(const float4*)(pc);        // row 2i:   patch 2k (.x,.y), 2k+1 (.z,.w)
        const float4 b = *(const float4*)(pc + WW);   // row 2i+1
        A[it] = a;
        B[it] = b;
        const float m0 = (a.x + a.y + b.x + b.y) * 0.25f;
        const float m1 = (a.z + a.w + b.z + b.w) * 0.25f;
        float e;
        e = a.x - m0 + EPSV; s0 += e * e;
        e = a.y - m0 + EPSV; s1 += e * e;
        e = b.x - m0 + EPSV; s2 += e * e;
        e = b.y - m0 + EPSV; s3 += e * e;
        e = a.z - m1 + EPSV; s4 += e * e;
        e = a.w - m1 + EPSV; s5 += e * e;
        e = b.z - m1 + EPSV; s6 += e * e;
        e = b.w - m1 + EPSV; s7 += e * e;
    }

    // Lane l and l^32 share k, differ in cb -> one shfl folds them.
    s0 += __shfl_xor(s0, 32);
    s1 += __shfl_xor(s1, 32);
    s2 += __shfl_xor(s2, 32);
    s3 += __shfl_xor(s3, 32);
    s4 += __shfl_xor(s4, 32);
    s5 += __shfl_xor(s5, 32);
    s6 += __shfl_xor(s6, 32);
    s7 += __shfl_xor(s7, 32);

    __shared__ float part[16][32][8];   // [wave][k][patchhalf*4 + e]  (16 KiB)
    __shared__ int sidx[TP];

    const int wave = t >> 6;
    if ((t & 63) < 32) {                // lanes 0..31 carry k = lane
        float* p = part[wave][k];
        p[0] = s0; p[1] = s1; p[2] = s2; p[3] = s3;
        p[4] = s4; p[5] = s5; p[6] = s6; p[7] = s7;
    }
    __syncthreads();

    if (t < TP) {                       // one thread per patch: sum 16 waves, argmax of 4
        const int kk = t >> 1;
        const int hf = (t & 1) * 4;
        float D0 = 0.f, D1 = 0.f, D2 = 0.f, D3 = 0.f;
#pragma unroll
        for (int w = 0; w < 16; ++w) {
            const float* p = part[w][kk] + hf;
            D0 += p[0];
            D1 += p[1];
            D2 += p[2];
            D3 += p[3];
        }
        int best = 0;
        float bv = D0;
        if (D1 > bv) { bv = D1; best = 1; }
        if (D2 > bv) { bv = D2; best = 2; }
        if (D3 > bv) { bv = D3; best = 3; }
        sidx[t] = best;
    }
    __syncthreads();

    const int e0 = sidx[2 * k];
    const int e1 = sidx[2 * k + 1];

#pragma unroll
    for (int it = 0; it < 8; ++it) {
        const int c = cb + 32 * it;
        const float4 a = A[it];
        const float4 b = B[it];
        const float v0 = (e0 == 0) ? a.x : (e0 == 1) ? a.y : (e0 == 2) ? b.x : b.y;
        const float v1 = (e1 == 0) ? a.z : (e1 == 1) ? a.w : (e1 == 2) ? b.z : b.w;
        v2f v;
        v.x = v0;
        v.y = v1;
        __builtin_nontemporal_store(v, (v2f*)(out + (size_t)c * LTOT + l0 + 2 * k));
    }
}

extern "C" void kernel_launch(void* const* d_in, const int* in_sizes, int n_in,
                              void* d_out, int out_size, void* d_ws, size_t ws_size,
                              hipStream_t stream) {
    const float* x = (const float*)d_in[0];
    float* out = (float*)d_out;
    fused_kernel<<<LTOT / TP, NTHREADS, 0, stream>>>(x, out);
}